// Round 1
// baseline (593.282 us; speedup 1.0000x reference)
//
#include <hip/hip_runtime.h>
#include <math.h>

#define M_SEQ 11520   // B*N
#define NNODE 360
#define NB    32
#define TT    64

// adj path: libm-accurate — gumbel/argmax pipeline bit-identical to proven state.
// GRU + decode: fast hardware exp (R12: absmax bit-unchanged).
__device__ __forceinline__ float fsigd(float x)  { return 1.0f / (1.0f + __expf(-x)); }
__device__ __forceinline__ float ftanhd(float x) { return 1.0f - 2.0f / (__expf(2.0f * x) + 1.0f); }

// ---------------- JAX threefry2x32, key=(0,42), partitionable, bits=y0^y1 ----
__device__ __forceinline__ unsigned rotl32(unsigned x, int n) { return (x << n) | (x >> (32 - n)); }

__device__ __forceinline__ void tf2x32(unsigned& x0, unsigned& x1)
{
    const unsigned k0 = 0u, k1 = 42u, k2 = 0u ^ 42u ^ 0x1BD11BDAu;
    x0 += k0; x1 += k1;
#define R4(a,b,c,d) \
    x0 += x1; x1 = rotl32(x1,a); x1 ^= x0; \
    x0 += x1; x1 = rotl32(x1,b); x1 ^= x0; \
    x0 += x1; x1 = rotl32(x1,c); x1 ^= x0; \
    x0 += x1; x1 = rotl32(x1,d); x1 ^= x0;
    R4(13,15,26,6)   x0 += k1; x1 += k2 + 1u;
    R4(17,29,16,24)  x0 += k2; x1 += k0 + 2u;
    R4(13,15,26,6)   x0 += k0; x1 += k1 + 3u;
    R4(17,29,16,24)  x0 += k1; x1 += k2 + 4u;
    R4(13,15,26,6)   x0 += k2; x1 += k0 + 5u;
#undef R4
}

__device__ __forceinline__ float jax_uniform(unsigned idx)
{
    unsigned x0 = 0u, x1 = idx;
    tf2x32(x0, x1);
    unsigned bits = x0 ^ x1;          // VERIFIED R5
    return __uint_as_float((bits >> 9) | 0x3f800000u) - 1.0f;
}

// broadcast within aligned 8-lane group via static-pattern ds_swizzle.
template<int K>
__device__ __forceinline__ void swz_fma(float h, const float* w0, const float* w1,
                                        const float* w2, float& g0, float& g1, float& g2)
{
    float hk = __int_as_float(
        __builtin_amdgcn_ds_swizzle(__float_as_int(h), (K << 5) | 0x18));
    g0 += hk * w0[K];
    g1 += hk * w1[K];
    g2 += hk * w2[K];
    if constexpr (K < 7)
        swz_fma<K + 1>(h, w0, w1, w2, g0, g1, g2);
}

// ---------------- GRU helpers (h-independent x-path separated) --------------
template<int I>
__device__ __forceinline__ void ldx(float* __restrict__ xv, const float* __restrict__ p)
{
    const float4* p4 = reinterpret_cast<const float4*>(p);
#pragma unroll
    for (int q = 0; q < I / 4; ++q) {
        float4 f = p4[q];
        xv[4*q] = f.x; xv[4*q+1] = f.y; xv[4*q+2] = f.z; xv[4*q+3] = f.w;
    }
}

template<int I>
__device__ __forceinline__ void xgates(const float* __restrict__ xv,
    const float* wx0, const float* wx1, const float* wx2,
    float bx0, float bx1, float bx2, float& xr, float& xz, float& xn)
{
    xr = bx0; xz = bx1; xn = bx2;   // same accumulation order as R12 -> bit-identical
#pragma unroll
    for (int k = 0; k < I; ++k) {
        xr += xv[k] * wx0[k];
        xz += xv[k] * wx1[k];
        xn += xv[k] * wx2[k];
    }
}

__device__ __forceinline__ float hstep(float h, float xr, float xz, float xn,
    const float* w0, const float* w1, const float* w2,
    float bh0, float bh1, float bh2)
{
    float gh0 = bh0, gh1 = bh1, gh2 = bh2;
    swz_fma<0>(h, w0, w1, w2, gh0, gh1, gh2);
    float r  = fsigd(xr + gh0);
    float z  = fsigd(xz + gh1);
    float nn = ftanhd(xn + r * gh2);
    return (1.f - z) * nn + z * h;
}

// ---------------- fused bidirectional GRU layer, 2-deep x pipeline ----------
template<int I>
__global__ __launch_bounds__(256) void gru_fused(
    const float* __restrict__ x,    // (M,64,I)
    const float* __restrict__ wih,  // (2,24,I)
    const float* __restrict__ whh,  // (2,24,8)
    const float* __restrict__ bih,  // (2,24)
    const float* __restrict__ bhh,  // (2,24)
    float* __restrict__ out)        // (M,64,16), dir writes its 8-half
{
    const int tid = blockIdx.x * 256 + threadIdx.x;
    const int j   = tid & 7;
    const int md  = tid >> 3;
    if (md >= M_SEQ * 2) return;
    const int m = md >> 1, dir = md & 1;

    float wx0[I], wx1[I], wx2[I];
    const float* WI = wih + dir * 24 * I;
#pragma unroll
    for (int k = 0; k < I; ++k) {
        wx0[k] = WI[j * I + k];
        wx1[k] = WI[(8 + j) * I + k];
        wx2[k] = WI[(16 + j) * I + k];
    }
    float w0[8], w1[8], w2[8];
    const float* WH = whh + dir * 192;
#pragma unroll
    for (int k = 0; k < 8; ++k) {
        w0[k] = WH[j * 8 + k];
        w1[k] = WH[(8 + j) * 8 + k];
        w2[k] = WH[(16 + j) * 8 + k];
    }
    const float bx0 = bih[dir*24 + j], bx1 = bih[dir*24 + 8 + j], bx2 = bih[dir*24 + 16 + j];
    const float bh0 = bhh[dir*24 + j], bh1 = bhh[dir*24 + 8 + j], bh2 = bhh[dir*24 + 16 + j];

    const float* xm = x + (size_t)m * TT * I;
    float* om = out + (size_t)m * TT * 16 + dir * 8 + j;

    const int tstep = dir ? -1 : 1;
    const int tbase = dir ? TT - 1 : 0;

    float h = 0.f;
    float xva[I], xvb[I];
    ldx<I>(xva, xm + (tbase) * I);                 // t(0)
    ldx<I>(xvb, xm + (tbase + tstep) * I);         // t(1)
    float cr, cz, cn;
    xgates<I>(xva, wx0, wx1, wx2, bx0, bx1, bx2, cr, cz, cn);   // gates(t(0))

    for (int tt = 0; tt < TT; tt += 2) {
        const int t0 = tbase + tstep * tt;
        const int t1 = t0 + tstep;
        // prefetch t(tt+2) into the slot whose data is already in c-gates
        if (tt + 2 < TT) ldx<I>(xva, xm + (t0 + 2 * tstep) * I);
        // gates(t(tt+1)) — h-independent, overlaps the recurrence stalls
        float nr, nz, nn;
        xgates<I>(xvb, wx0, wx1, wx2, bx0, bx1, bx2, nr, nz, nn);
        h = hstep(h, cr, cz, cn, w0, w1, w2, bh0, bh1, bh2);
        om[t0 * 16] = h;
        // prefetch t(tt+3); xvb's content was consumed into n-gates above
        if (tt + 3 < TT) ldx<I>(xvb, xm + (t0 + 3 * tstep) * I);
        h = hstep(h, nr, nz, nn, w0, w1, w2, bh0, bh1, bh2);
        om[t1 * 16] = h;
        // gates(t(tt+2)) from xva — placed last: max load->use distance
        xgates<I>(xva, wx0, wx1, wx2, bx0, bx1, bx2, cr, cz, cn);
    }
}

// ---------------- feat MLP (pure FMA) ---------------------------------------
__global__ void feat_kernel(const float* __restrict__ gout,
                            const float* __restrict__ l1w, const float* __restrict__ l1b,
                            const float* __restrict__ l2w, const float* __restrict__ l2b,
                            float* __restrict__ feat)
{
    int m = blockIdx.x * blockDim.x + threadIdx.x;
    if (m >= M_SEQ) return;
    const float* xp = gout + (size_t)m * TT * 16 + (TT - 1) * 16;
    float xv[16];
#pragma unroll
    for (int i = 0; i < 16; ++i) xv[i] = xp[i];
    float h1[8];
#pragma unroll
    for (int o = 0; o < 8; ++o) {
        float a = 0.f;
#pragma unroll
        for (int f = 0; f < 16; ++f) a += xv[f] * l1w[o * 16 + f];
        a += l1b[o];
        h1[o] = (a >= 0.f) ? a : 0.2f * a;
    }
#pragma unroll
    for (int o = 0; o < 8; ++o) {
        float a = 0.f;
#pragma unroll
        for (int f = 0; f < 8; ++f) a += h1[f] * l2w[o * 8 + f];
        feat[(size_t)m * 8 + o] = a + l2b[o];
    }
}

// ---------------- adjacency (libm — bit-identical to proven state) ----------
__global__ void adj_kernel(const float* __restrict__ feat,
                           const float* __restrict__ tptr,
                           int* __restrict__ colp, float* __restrict__ vp)
{
    const int gw   = (blockIdx.x * blockDim.x + threadIdx.x) >> 6;
    const int lane = threadIdx.x & 63;
    if (gw >= NB * NNODE) return;
    const int b = gw / NNODE;
    const int n = gw - b * NNODE;
    const float T = tptr[0];
    const float* fb = feat + (size_t)b * NNODE * 8;
    float fn[8];
#pragma unroll
    for (int k = 0; k < 8; ++k) fn[k] = fb[(size_t)n * 8 + k];

    float sv[6];
    float mval = -3.0e38f; int midx = 1 << 30;
#pragma unroll
    for (int s = 0; s < 6; ++s) {
        int p = s * 64 + lane;
        float xs = -3.0e38f;
        if (p < NNODE) {
            const float* fp = fb + (size_t)p * 8;
            float d = 0.f;
#pragma unroll
            for (int k = 0; k < 8; ++k) d += fn[k] * fp[k];
            unsigned idx = (unsigned)gw * 360u + (unsigned)p;
            float u   = jax_uniform(idx);
            float gum = -logf(-logf(u + 1e-10f) + 1e-10f);
            xs = (d + gum) / T;
            if (xs > mval) { mval = xs; midx = p; }
        }
        sv[s] = xs;
    }
    for (int off = 32; off > 0; off >>= 1) {   // ties -> smaller index
        float ov = __shfl_xor(mval, off);
        int   oi = __shfl_xor(midx, off);
        if (ov > mval || (ov == mval && oi < midx)) { mval = ov; midx = oi; }
    }
    float ssum = 0.f;
#pragma unroll
    for (int s = 0; s < 6; ++s) {
        int p = s * 64 + lane;
        if (p < NNODE) ssum += expf(sv[s] - mval);
    }
    for (int off = 32; off > 0; off >>= 1) ssum += __shfl_xor(ssum, off);
    if (lane == 0) {
        float ys = 1.0f / ssum;
        float v  = ys + (1.0f - ys);
        if (midx == n) v = 0.0f;
        colp[gw] = midx;
        vp[gw]   = v;
    }
}

// ---------------- DCGRU cell, one-barrier-per-layer form ---------------------
// Thread n computes its own r,u,c AND redundantly recomputes r at c1,c2 from
// gathered o/h at c1..c4 (one-hot adjacency => closure is the col-chain).
// Same formula order as the owning thread => bit-identical values.
__device__ __forceinline__ float dc_cell(
    float o, float o1, float o2, float o3, float o4,
    float h, float h1, float h2, float h3, float h4,
    float v, float vv, float va, float vva, float vb, float vvb,
    const float (&W)[12], float bgr, float bgu,
    const float (&C)[6], float cb)
{
    float f1 = v * o1,  f2 = vv * o2 - o;
    float f4 = v * h1,  f5 = vv * h2 - h;
    float r  = fsigd(o*W[0] + f1*W[2] + f2*W[4] + h*W[6] + f4*W[8] + f5*W[10] + bgr);
    float u  = fsigd(o*W[1] + f1*W[3] + f2*W[5] + h*W[7] + f4*W[9] + f5*W[11] + bgu);
    float rh = r * h;
    // redundant r at c1 (node c1's own v is va, its vv is vva)
    float g1 = va * o2, g2 = vva * o3 - o1;
    float g4 = va * h2, g5 = vva * h3 - h1;
    float ra = fsigd(o1*W[0] + g1*W[2] + g2*W[4] + h1*W[6] + g4*W[8] + g5*W[10] + bgr);
    float rha = ra * h1;
    // redundant r at c2
    float k1 = vb * o3, k2 = vvb * o4 - o2;
    float k4 = vb * h3, k5 = vvb * h4 - h2;
    float rb = fsigd(o2*W[0] + k1*W[2] + k2*W[4] + h2*W[6] + k4*W[8] + k5*W[10] + bgr);
    float rhb = rb * h2;
    float cnd = ftanhd(o*C[0] + f1*C[1] + f2*C[2] + rh*C[3]
                       + (v*rha)*C[4] + (vv*rhb - rh)*C[5] + cb);
    return u * h + (1.f - u) * cnd;
}

// decode: 3 barriers/step (was 6), all weights in VGPRs (was LDS re-reads),
// parity double-buffered state packed as [node][{h0,h1,h2,o_next}] so one
// ds_read_b128 per chain index fetches everything the whole step needs.
__global__ __launch_bounds__(384, 1) void decode_kernel(
    const float* __restrict__ rec,   // (B, N, T)
    const int*   __restrict__ colp, const float* __restrict__ vp,
    const float* __restrict__ egw, const float* __restrict__ egb,
    const float* __restrict__ ecw, const float* __restrict__ ecb,
    const float* __restrict__ dgw, const float* __restrict__ dgb,
    const float* __restrict__ dcw, const float* __restrict__ dcb,
    const float* __restrict__ pw,  const float* __restrict__ pb,
    float* __restrict__ outp)        // (B, N, T)
{
    __shared__ __align__(16) float s_h[2][NNODE][4]; // [parity][node][h0,h1,h2,o_next]
    __shared__ float s_v[NNODE];
    __shared__ int   s_c[NNODE];

    const int b = blockIdx.x;
    const int n = threadIdx.x;
    const bool act = n < NNODE;

    float inp0 = 0.f;
    if (act) {
        s_c[n] = colp[b * NNODE + n];
        s_v[n] = vp[b * NNODE + n];
        inp0   = rec[((size_t)b * NNODE + n) * TT + 0];
        s_h[0][n][0] = 0.f; s_h[0][n][1] = 0.f; s_h[0][n][2] = 0.f;
        s_h[0][n][3] = inp0;
    }
    __syncthreads();

    int c1 = 0, c2 = 0, c3 = 0, c4 = 0;
    float v = 0.f, vv = 0.f, va = 0.f, vva = 0.f, vb = 0.f, vvb = 0.f;
    if (act) {
        c1 = s_c[n]; c2 = s_c[c1]; c3 = s_c[c2]; c4 = s_c[c3];
        v  = s_v[n];
        float sv1 = s_v[c1], sv2 = s_v[c2], sv3 = s_v[c3];
        vv  = 2.f * v   * sv1;
        va  = sv1; vva = 2.f * sv1 * sv2;
        vb  = sv2; vvb = 2.f * sv2 * sv3;
    }
    const float projw = pw[0], projb = pb[0];
    float hreg[3] = {0.f, 0.f, 0.f};

    // ---- encoder weights -> registers (uniform, loop-invariant) ----
    float W0[12], W1[12], W2[12], C0[6], C1[6], C2[6];
    float b0r, b0u, b1r, b1u, b2r, b2u, cb0, cb1, cb2;
#pragma unroll
    for (int k = 0; k < 12; ++k) { W0[k] = egw[k]; W1[k] = egw[12+k]; W2[k] = egw[24+k]; }
#pragma unroll
    for (int k = 0; k < 6;  ++k) { C0[k] = ecw[k]; C1[k] = ecw[6+k];  C2[k] = ecw[12+k]; }
    b0r = egb[0]; b0u = egb[1]; b1r = egb[2]; b1u = egb[3]; b2r = egb[4]; b2u = egb[5];
    cb0 = ecb[0]; cb1 = ecb[1]; cb2 = ecb[2];

    float o_own = inp0;
    int p = 0;
    // ---------------- encoder ----------------
    for (int t = 0; t < TT; ++t) {
        float nx = (act && t + 1 < TT) ? rec[((size_t)b * NNODE + n) * TT + t + 1] : 0.f;
        const int q = p ^ 1;
        const float4* hp = reinterpret_cast<const float4*>(&s_h[p][0][0]);
        float4 F1 = make_float4(0,0,0,0), F2 = F1, F3 = F1, F4 = F1;
        if (act) { F1 = hp[c1]; F2 = hp[c2]; F3 = hp[c3]; F4 = hp[c4]; }
        // layer 0: o = staged inputs (lane .w)
        float hn0 = dc_cell(o_own, F1.w, F2.w, F3.w, F4.w,
                            hreg[0], F1.x, F2.x, F3.x, F4.x,
                            v, vv, va, vva, vb, vvb, W0, b0r, b0u, C0, cb0);
        hreg[0] = hn0;
        if (act) s_h[q][n][0] = hn0;
        __syncthreads();
        float oa = 0.f, ob = 0.f, oc = 0.f, od = 0.f;
        if (act) { oa = s_h[q][c1][0]; ob = s_h[q][c2][0]; oc = s_h[q][c3][0]; od = s_h[q][c4][0]; }
        float hn1 = dc_cell(hn0, oa, ob, oc, od,
                            hreg[1], F1.y, F2.y, F3.y, F4.y,
                            v, vv, va, vva, vb, vvb, W1, b1r, b1u, C1, cb1);
        hreg[1] = hn1;
        if (act) s_h[q][n][1] = hn1;
        __syncthreads();
        if (act) { oa = s_h[q][c1][1]; ob = s_h[q][c2][1]; oc = s_h[q][c3][1]; od = s_h[q][c4][1]; }
        float hn2 = dc_cell(hn1, oa, ob, oc, od,
                            hreg[2], F1.z, F2.z, F3.z, F4.z,
                            v, vv, va, vva, vb, vvb, W2, b2r, b2u, C2, cb2);
        hreg[2] = hn2;
        if (act) { s_h[q][n][2] = hn2; s_h[q][n][3] = nx; }  // stage next input
        __syncthreads();
        o_own = nx; p = q;
    }
    // after 64 steps p is back to 0; s_h[0][n][3] == 0 == first decoder input.

    // ---- decoder weights -> registers ----
#pragma unroll
    for (int k = 0; k < 12; ++k) { W0[k] = dgw[k]; W1[k] = dgw[12+k]; W2[k] = dgw[24+k]; }
#pragma unroll
    for (int k = 0; k < 6;  ++k) { C0[k] = dcw[k]; C1[k] = dcw[6+k];  C2[k] = dcw[12+k]; }
    b0r = dgb[0]; b0u = dgb[1]; b1r = dgb[2]; b1u = dgb[3]; b2r = dgb[4]; b2u = dgb[5];
    cb0 = dcb[0]; cb1 = dcb[1]; cb2 = dcb[2];

    // ---------------- decoder ----------------
    float dinp = 0.f;
    for (int t = 0; t < TT; ++t) {
        const int q = p ^ 1;
        const float4* hp = reinterpret_cast<const float4*>(&s_h[p][0][0]);
        float4 F1 = make_float4(0,0,0,0), F2 = F1, F3 = F1, F4 = F1;
        if (act) { F1 = hp[c1]; F2 = hp[c2]; F3 = hp[c3]; F4 = hp[c4]; }
        float hn0 = dc_cell(dinp, F1.w, F2.w, F3.w, F4.w,
                            hreg[0], F1.x, F2.x, F3.x, F4.x,
                            v, vv, va, vva, vb, vvb, W0, b0r, b0u, C0, cb0);
        hreg[0] = hn0;
        if (act) s_h[q][n][0] = hn0;
        __syncthreads();
        float oa = 0.f, ob = 0.f, oc = 0.f, od = 0.f;
        if (act) { oa = s_h[q][c1][0]; ob = s_h[q][c2][0]; oc = s_h[q][c3][0]; od = s_h[q][c4][0]; }
        float hn1 = dc_cell(hn0, oa, ob, oc, od,
                            hreg[1], F1.y, F2.y, F3.y, F4.y,
                            v, vv, va, vva, vb, vvb, W1, b1r, b1u, C1, cb1);
        hreg[1] = hn1;
        if (act) s_h[q][n][1] = hn1;
        __syncthreads();
        if (act) { oa = s_h[q][c1][1]; ob = s_h[q][c2][1]; oc = s_h[q][c3][1]; od = s_h[q][c4][1]; }
        float hn2 = dc_cell(hn1, oa, ob, oc, od,
                            hreg[2], F1.z, F2.z, F3.z, F4.z,
                            v, vv, va, vva, vb, vvb, W2, b2r, b2u, C2, cb2);
        hreg[2] = hn2;
        float proj = hn2 * projw + projb;
        if (act) {
            s_h[q][n][2] = hn2;
            s_h[q][n][3] = proj;                 // stage next decoder input
            outp[((size_t)b * NNODE + n) * TT + t] = proj;
        }
        __syncthreads();
        dinp = proj; p = q;
    }
}

// ---------------- host launcher ---------------------------------------------
extern "C" void kernel_launch(void* const* d_in, const int* in_sizes, int n_in,
                              void* d_out, int out_size, void* d_ws, size_t ws_size,
                              hipStream_t stream)
{
    (void)in_sizes; (void)n_in; (void)out_size; (void)ws_size;
    const float* full_seq = (const float*)d_in[0];   // (M,64,8)
    const float* rec_seq  = (const float*)d_in[1];   // (32,360,64)
    const float* temp     = (const float*)d_in[3];
    const float* g0wih    = (const float*)d_in[4];
    const float* g0whh    = (const float*)d_in[5];
    const float* g0bih    = (const float*)d_in[6];
    const float* g0bhh    = (const float*)d_in[7];
    const float* gwih     = (const float*)d_in[8];   // (3,2,24,16)
    const float* gwhh     = (const float*)d_in[9];   // (3,2,24,8)
    const float* gbih     = (const float*)d_in[10];
    const float* gbhh     = (const float*)d_in[11];
    const float* l1w      = (const float*)d_in[12];
    const float* l1b      = (const float*)d_in[13];
    const float* l2w      = (const float*)d_in[14];
    const float* l2b      = (const float*)d_in[15];
    const float* enc_gw   = (const float*)d_in[16];
    const float* enc_gb   = (const float*)d_in[17];
    const float* enc_cw   = (const float*)d_in[18];
    const float* enc_cb   = (const float*)d_in[19];
    const float* dec_gw   = (const float*)d_in[20];
    const float* dec_gb   = (const float*)d_in[21];
    const float* dec_cw   = (const float*)d_in[22];
    const float* dec_cb   = (const float*)d_in[23];
    const float* proj_w   = (const float*)d_in[24];
    const float* proj_b   = (const float*)d_in[25];
    float* outp = (float*)d_out;

    // ws: small-first; bufA+bufB ping-pong = 94.85 MB total (proven size)
    float* ws   = (float*)d_ws;
    float* feat = ws;                                     // (M,8)
    float* vbuf = feat + (size_t)M_SEQ * 8;               // (M,)
    int*   cbuf = (int*)(vbuf + M_SEQ);                   // (M,)
    float* bufA = (float*)(cbuf + M_SEQ);                 // (M,64,16)
    float* bufB = bufA + (size_t)M_SEQ * TT * 16;         // (M,64,16)

    const int ggru = (M_SEQ * 2 * 8) / 256;   // 720 blocks
    gru_fused<8><<<ggru, 256, 0, stream>>>(full_seq, g0wih, g0whh, g0bih, g0bhh, bufA);
    gru_fused<16><<<ggru, 256, 0, stream>>>(bufA, gwih + 0 * 768, gwhh + 0 * 384,
                                            gbih + 0 * 48, gbhh + 0 * 48, bufB);
    gru_fused<16><<<ggru, 256, 0, stream>>>(bufB, gwih + 1 * 768, gwhh + 1 * 384,
                                            gbih + 1 * 48, gbhh + 1 * 48, bufA);
    gru_fused<16><<<ggru, 256, 0, stream>>>(bufA, gwih + 2 * 768, gwhh + 2 * 384,
                                            gbih + 2 * 48, gbhh + 2 * 48, bufB);
    feat_kernel<<<M_SEQ / 256, 256, 0, stream>>>(bufB, l1w, l1b, l2w, l2b, feat);
    adj_kernel<<<(NB * NNODE) / 4, 256, 0, stream>>>(feat, temp, cbuf, vbuf);
    decode_kernel<<<NB, 384, 0, stream>>>(rec_seq, cbuf, vbuf,
                                          enc_gw, enc_gb, enc_cw, enc_cb,
                                          dec_gw, dec_gb, dec_cw, dec_cb,
                                          proj_w, proj_b, outp);
}

// Round 2
// 527.497 us; speedup vs baseline: 1.1247x; 1.1247x over previous
//
#include <hip/hip_runtime.h>
#include <math.h>

#define M_SEQ 11520   // B*N
#define NNODE 360
#define NB    32
#define TT    64

// adj path: libm-accurate — gumbel/argmax pipeline bit-identical to proven state.
// GRU + decode: fast hardware exp (R12: absmax bit-unchanged).
__device__ __forceinline__ float fsigd(float x)  { return 1.0f / (1.0f + __expf(-x)); }
__device__ __forceinline__ float ftanhd(float x) { return 1.0f - 2.0f / (__expf(2.0f * x) + 1.0f); }

// ---------------- JAX threefry2x32, key=(0,42), partitionable, bits=y0^y1 ----
__device__ __forceinline__ unsigned rotl32(unsigned x, int n) { return (x << n) | (x >> (32 - n)); }

__device__ __forceinline__ void tf2x32(unsigned& x0, unsigned& x1)
{
    const unsigned k0 = 0u, k1 = 42u, k2 = 0u ^ 42u ^ 0x1BD11BDAu;
    x0 += k0; x1 += k1;
#define R4(a,b,c,d) \
    x0 += x1; x1 = rotl32(x1,a); x1 ^= x0; \
    x0 += x1; x1 = rotl32(x1,b); x1 ^= x0; \
    x0 += x1; x1 = rotl32(x1,c); x1 ^= x0; \
    x0 += x1; x1 = rotl32(x1,d); x1 ^= x0;
    R4(13,15,26,6)   x0 += k1; x1 += k2 + 1u;
    R4(17,29,16,24)  x0 += k2; x1 += k0 + 2u;
    R4(13,15,26,6)   x0 += k0; x1 += k1 + 3u;
    R4(17,29,16,24)  x0 += k1; x1 += k2 + 4u;
    R4(13,15,26,6)   x0 += k2; x1 += k0 + 5u;
#undef R4
}

__device__ __forceinline__ float jax_uniform(unsigned idx)
{
    unsigned x0 = 0u, x1 = idx;
    tf2x32(x0, x1);
    unsigned bits = x0 ^ x1;          // VERIFIED R5
    return __uint_as_float((bits >> 9) | 0x3f800000u) - 1.0f;
}

// broadcast within aligned 8-lane group via static-pattern ds_swizzle.
template<int K>
__device__ __forceinline__ void swz_fma(float h, const float* w0, const float* w1,
                                        const float* w2, float& g0, float& g1, float& g2)
{
    float hk = __int_as_float(
        __builtin_amdgcn_ds_swizzle(__float_as_int(h), (K << 5) | 0x18));
    g0 += hk * w0[K];
    g1 += hk * w1[K];
    g2 += hk * w2[K];
    if constexpr (K < 7)
        swz_fma<K + 1>(h, w0, w1, w2, g0, g1, g2);
}

// ---------------- GRU helpers (h-independent x-path separated) --------------
template<int I>
__device__ __forceinline__ void ldx(float* __restrict__ xv, const float* __restrict__ p)
{
    const float4* p4 = reinterpret_cast<const float4*>(p);
#pragma unroll
    for (int q = 0; q < I / 4; ++q) {
        float4 f = p4[q];
        xv[4*q] = f.x; xv[4*q+1] = f.y; xv[4*q+2] = f.z; xv[4*q+3] = f.w;
    }
}

template<int I>
__device__ __forceinline__ void xgates(const float* __restrict__ xv,
    const float* wx0, const float* wx1, const float* wx2,
    float bx0, float bx1, float bx2, float& xr, float& xz, float& xn)
{
    xr = bx0; xz = bx1; xn = bx2;   // same accumulation order as R12 -> bit-identical
#pragma unroll
    for (int k = 0; k < I; ++k) {
        xr += xv[k] * wx0[k];
        xz += xv[k] * wx1[k];
        xn += xv[k] * wx2[k];
    }
}

__device__ __forceinline__ float hstep(float h, float xr, float xz, float xn,
    const float* w0, const float* w1, const float* w2,
    float bh0, float bh1, float bh2)
{
    float gh0 = bh0, gh1 = bh1, gh2 = bh2;
    swz_fma<0>(h, w0, w1, w2, gh0, gh1, gh2);
    float r  = fsigd(xr + gh0);
    float z  = fsigd(xz + gh1);
    float nn = ftanhd(xn + r * gh2);
    return (1.f - z) * nn + z * h;
}

// ---------------- fused bidirectional GRU layer, 2-deep x pipeline ----------
template<int I>
__global__ __launch_bounds__(256) void gru_fused(
    const float* __restrict__ x,    // (M,64,I)
    const float* __restrict__ wih,  // (2,24,I)
    const float* __restrict__ whh,  // (2,24,8)
    const float* __restrict__ bih,  // (2,24)
    const float* __restrict__ bhh,  // (2,24)
    float* __restrict__ out)        // (M,64,16), dir writes its 8-half
{
    const int tid = blockIdx.x * 256 + threadIdx.x;
    const int j   = tid & 7;
    const int md  = tid >> 3;
    if (md >= M_SEQ * 2) return;
    const int m = md >> 1, dir = md & 1;

    float wx0[I], wx1[I], wx2[I];
    const float* WI = wih + dir * 24 * I;
#pragma unroll
    for (int k = 0; k < I; ++k) {
        wx0[k] = WI[j * I + k];
        wx1[k] = WI[(8 + j) * I + k];
        wx2[k] = WI[(16 + j) * I + k];
    }
    float w0[8], w1[8], w2[8];
    const float* WH = whh + dir * 192;
#pragma unroll
    for (int k = 0; k < 8; ++k) {
        w0[k] = WH[j * 8 + k];
        w1[k] = WH[(8 + j) * 8 + k];
        w2[k] = WH[(16 + j) * 8 + k];
    }
    const float bx0 = bih[dir*24 + j], bx1 = bih[dir*24 + 8 + j], bx2 = bih[dir*24 + 16 + j];
    const float bh0 = bhh[dir*24 + j], bh1 = bhh[dir*24 + 8 + j], bh2 = bhh[dir*24 + 16 + j];

    const float* xm = x + (size_t)m * TT * I;
    float* om = out + (size_t)m * TT * 16 + dir * 8 + j;

    const int tstep = dir ? -1 : 1;
    const int tbase = dir ? TT - 1 : 0;

    float h = 0.f;
    float xva[I], xvb[I];
    ldx<I>(xva, xm + (tbase) * I);                 // t(0)
    ldx<I>(xvb, xm + (tbase + tstep) * I);         // t(1)
    float cr, cz, cn;
    xgates<I>(xva, wx0, wx1, wx2, bx0, bx1, bx2, cr, cz, cn);   // gates(t(0))

    for (int tt = 0; tt < TT; tt += 2) {
        const int t0 = tbase + tstep * tt;
        const int t1 = t0 + tstep;
        // prefetch t(tt+2) into the slot whose data is already in c-gates
        if (tt + 2 < TT) ldx<I>(xva, xm + (t0 + 2 * tstep) * I);
        // gates(t(tt+1)) — h-independent, overlaps the recurrence stalls
        float nr, nz, nn;
        xgates<I>(xvb, wx0, wx1, wx2, bx0, bx1, bx2, nr, nz, nn);
        h = hstep(h, cr, cz, cn, w0, w1, w2, bh0, bh1, bh2);
        om[t0 * 16] = h;
        // prefetch t(tt+3); xvb's content was consumed into n-gates above
        if (tt + 3 < TT) ldx<I>(xvb, xm + (t0 + 3 * tstep) * I);
        h = hstep(h, nr, nz, nn, w0, w1, w2, bh0, bh1, bh2);
        om[t1 * 16] = h;
        // gates(t(tt+2)) from xva — placed last: max load->use distance
        xgates<I>(xva, wx0, wx1, wx2, bx0, bx1, bx2, cr, cz, cn);
    }
}

// ---------------- feat MLP (pure FMA) ---------------------------------------
__global__ void feat_kernel(const float* __restrict__ gout,
                            const float* __restrict__ l1w, const float* __restrict__ l1b,
                            const float* __restrict__ l2w, const float* __restrict__ l2b,
                            float* __restrict__ feat)
{
    int m = blockIdx.x * blockDim.x + threadIdx.x;
    if (m >= M_SEQ) return;
    const float* xp = gout + (size_t)m * TT * 16 + (TT - 1) * 16;
    float xv[16];
#pragma unroll
    for (int i = 0; i < 16; ++i) xv[i] = xp[i];
    float h1[8];
#pragma unroll
    for (int o = 0; o < 8; ++o) {
        float a = 0.f;
#pragma unroll
        for (int f = 0; f < 16; ++f) a += xv[f] * l1w[o * 16 + f];
        a += l1b[o];
        h1[o] = (a >= 0.f) ? a : 0.2f * a;
    }
#pragma unroll
    for (int o = 0; o < 8; ++o) {
        float a = 0.f;
#pragma unroll
        for (int f = 0; f < 8; ++f) a += h1[f] * l2w[o * 8 + f];
        feat[(size_t)m * 8 + o] = a + l2b[o];
    }
}

// ---------------- adjacency (libm — bit-identical to proven state) ----------
__global__ void adj_kernel(const float* __restrict__ feat,
                           const float* __restrict__ tptr,
                           int* __restrict__ colp, float* __restrict__ vp)
{
    const int gw   = (blockIdx.x * blockDim.x + threadIdx.x) >> 6;
    const int lane = threadIdx.x & 63;
    if (gw >= NB * NNODE) return;
    const int b = gw / NNODE;
    const int n = gw - b * NNODE;
    const float T = tptr[0];
    const float* fb = feat + (size_t)b * NNODE * 8;
    float fn[8];
#pragma unroll
    for (int k = 0; k < 8; ++k) fn[k] = fb[(size_t)n * 8 + k];

    float sv[6];
    float mval = -3.0e38f; int midx = 1 << 30;
#pragma unroll
    for (int s = 0; s < 6; ++s) {
        int p = s * 64 + lane;
        float xs = -3.0e38f;
        if (p < NNODE) {
            const float* fp = fb + (size_t)p * 8;
            float d = 0.f;
#pragma unroll
            for (int k = 0; k < 8; ++k) d += fn[k] * fp[k];
            unsigned idx = (unsigned)gw * 360u + (unsigned)p;
            float u   = jax_uniform(idx);
            float gum = -logf(-logf(u + 1e-10f) + 1e-10f);
            xs = (d + gum) / T;
            if (xs > mval) { mval = xs; midx = p; }
        }
        sv[s] = xs;
    }
    for (int off = 32; off > 0; off >>= 1) {   // ties -> smaller index
        float ov = __shfl_xor(mval, off);
        int   oi = __shfl_xor(midx, off);
        if (ov > mval || (ov == mval && oi < midx)) { mval = ov; midx = oi; }
    }
    float ssum = 0.f;
#pragma unroll
    for (int s = 0; s < 6; ++s) {
        int p = s * 64 + lane;
        if (p < NNODE) ssum += expf(sv[s] - mval);
    }
    for (int off = 32; off > 0; off >>= 1) ssum += __shfl_xor(ssum, off);
    if (lane == 0) {
        float ys = 1.0f / ssum;
        float v  = ys + (1.0f - ys);
        if (midx == n) v = 0.0f;
        colp[gw] = midx;
        vp[gw]   = v;
    }
}

// ---------------- DCGRU layer: R0 arithmetic, u hidden under rh-gather -------
// Expressions and evaluation order are IDENTICAL to the proven R0 run3 ->
// bit-identical results. Only the scheduling differs: the rh gathers are
// issued before u is computed, so u's VALU hides under the LDS latency.
__device__ __forceinline__ void dc_layer(
    float o_own, float oa, float ob,          // layer input at n, c1, c2
    float& hn, float ha, float hb,            // layer state at n (updated), c1, c2
    float v, float vv, int c1, int c2, bool act, int n,
    const float* __restrict__ W, float bgr, float bgu,
    const float* __restrict__ C, float cb,
    float* __restrict__ s_rh)
{
    float f1 = v * oa, f2 = vv * ob - o_own;
    float f4 = v * ha, f5 = vv * hb - hn;
    float r  = fsigd(o_own*W[0] + f1*W[2] + f2*W[4] + hn*W[6] + f4*W[8] + f5*W[10] + bgr);
    float rh = r * hn;
    if (act) s_rh[n] = rh;
    __syncthreads();
    // issue gathers first, then compute u (independent of r) under the latency
    float rha = s_rh[c1], rhb = s_rh[c2];
    float u  = fsigd(o_own*W[1] + f1*W[3] + f2*W[5] + hn*W[7] + f4*W[9] + f5*W[11] + bgu);
    float cnd = ftanhd(o_own*C[0] + f1*C[1] + f2*C[2] + rh*C[3]
                       + (v*rha)*C[4] + (vv*rhb - rh)*C[5] + cb);
    hn = u * hn + (1.f - u) * cnd;
}

// decode: R0 structure (6 barriers/step, scalar LDS layout) with
//  - parity double-buffered s_h / s_x: previous-step state is read-only, so
//    all 8 cross-node gathers for the whole step issue together at step top
//  - all weights in registers/SGPRs (no LDS weight re-reads on the chain)
__global__ __launch_bounds__(384, 1) void decode_kernel(
    const float* __restrict__ rec,   // (B, N, T)
    const int*   __restrict__ colp, const float* __restrict__ vp,
    const float* __restrict__ egw, const float* __restrict__ egb,
    const float* __restrict__ ecw, const float* __restrict__ ecb,
    const float* __restrict__ dgw, const float* __restrict__ dgb,
    const float* __restrict__ dcw, const float* __restrict__ dcb,
    const float* __restrict__ pw,  const float* __restrict__ pb,
    float* __restrict__ outp)        // (B, N, T)
{
    __shared__ float s_h[2][3][NNODE];   // [parity][layer][node], scalar 4B stride
    __shared__ float s_x[2][NNODE];      // [parity][node] layer-0 input staging
    __shared__ float s_o[NNODE];         // intra-step layer output exchange
    __shared__ float s_rh[NNODE];
    __shared__ float s_v[NNODE];
    __shared__ int   s_c[NNODE];

    const int b = blockIdx.x;
    const int n = threadIdx.x;
    const bool act = n < NNODE;

    float inp0 = 0.f;
    if (act) {
        s_c[n] = colp[b * NNODE + n];
        s_v[n] = vp[b * NNODE + n];
        inp0   = rec[((size_t)b * NNODE + n) * TT + 0];
        s_h[0][0][n] = 0.f; s_h[0][1][n] = 0.f; s_h[0][2][n] = 0.f;
        s_x[0][n] = inp0;
    }
    __syncthreads();

    int c1 = 0, c2 = 0;
    float v = 0.f, vv = 0.f;
    if (act) {
        c1 = s_c[n];
        c2 = s_c[c1];
        v  = s_v[n];
        vv = 2.f * v * s_v[c1];
    }
    const float projw = pw[0], projb = pb[0];
    float hreg[3] = {0.f, 0.f, 0.f};

    // ---- encoder weights -> registers (uniform loads -> SGPRs) ----
    float Wg[36], Bg[6], Wc[18], Cb[3];
#pragma unroll
    for (int k = 0; k < 36; ++k) Wg[k] = egw[k];
#pragma unroll
    for (int k = 0; k < 6;  ++k) Bg[k] = egb[k];
#pragma unroll
    for (int k = 0; k < 18; ++k) Wc[k] = ecw[k];
#pragma unroll
    for (int k = 0; k < 3;  ++k) Cb[k] = ecb[k];

    float o_own = inp0;
    int p = 0;
    // ---------------- encoder ----------------
    for (int t = 0; t < TT; ++t) {
        float nx = (act && t + 1 < TT) ? rec[((size_t)b * NNODE + n) * TT + t + 1] : 0.f;
        // all previous-step-state gathers issue together (parity p is read-only)
        float xa  = s_x[p][c1],    xb  = s_x[p][c2];
        float h0a = s_h[p][0][c1], h0b = s_h[p][0][c2];
        float h1a = s_h[p][1][c1], h1b = s_h[p][1][c2];
        float h2a = s_h[p][2][c1], h2b = s_h[p][2][c2];
        const int q = p ^ 1;
        // layer 0
        dc_layer(o_own, xa, xb, hreg[0], h0a, h0b, v, vv, c1, c2, act, n,
                 Wg, Bg[0], Bg[1], Wc, Cb[0], s_rh);
        if (act) { s_h[q][0][n] = hreg[0]; s_o[n] = hreg[0]; }
        __syncthreads();
        // layer 1
        float oa = s_o[c1], ob = s_o[c2];
        dc_layer(hreg[0], oa, ob, hreg[1], h1a, h1b, v, vv, c1, c2, act, n,
                 Wg + 12, Bg[2], Bg[3], Wc + 6, Cb[1], s_rh);
        if (act) { s_h[q][1][n] = hreg[1]; s_o[n] = hreg[1]; }
        __syncthreads();
        // layer 2
        oa = s_o[c1]; ob = s_o[c2];
        dc_layer(hreg[1], oa, ob, hreg[2], h2a, h2b, v, vv, c1, c2, act, n,
                 Wg + 24, Bg[4], Bg[5], Wc + 12, Cb[2], s_rh);
        if (act) { s_h[q][2][n] = hreg[2]; s_x[q][n] = nx; }  // stage next input
        __syncthreads();
        o_own = nx; p = q;
    }
    // 64 steps -> p back to 0; s_x[0][n] == 0 == first decoder input.

    // ---- decoder weights -> registers ----
#pragma unroll
    for (int k = 0; k < 36; ++k) Wg[k] = dgw[k];
#pragma unroll
    for (int k = 0; k < 6;  ++k) Bg[k] = dgb[k];
#pragma unroll
    for (int k = 0; k < 18; ++k) Wc[k] = dcw[k];
#pragma unroll
    for (int k = 0; k < 3;  ++k) Cb[k] = dcb[k];

    // ---------------- decoder ----------------
    float dinp = 0.f;
    for (int t = 0; t < TT; ++t) {
        float xa  = s_x[p][c1],    xb  = s_x[p][c2];
        float h0a = s_h[p][0][c1], h0b = s_h[p][0][c2];
        float h1a = s_h[p][1][c1], h1b = s_h[p][1][c2];
        float h2a = s_h[p][2][c1], h2b = s_h[p][2][c2];
        const int q = p ^ 1;
        dc_layer(dinp, xa, xb, hreg[0], h0a, h0b, v, vv, c1, c2, act, n,
                 Wg, Bg[0], Bg[1], Wc, Cb[0], s_rh);
        if (act) { s_h[q][0][n] = hreg[0]; s_o[n] = hreg[0]; }
        __syncthreads();
        float oa = s_o[c1], ob = s_o[c2];
        dc_layer(hreg[0], oa, ob, hreg[1], h1a, h1b, v, vv, c1, c2, act, n,
                 Wg + 12, Bg[2], Bg[3], Wc + 6, Cb[1], s_rh);
        if (act) { s_h[q][1][n] = hreg[1]; s_o[n] = hreg[1]; }
        __syncthreads();
        oa = s_o[c1]; ob = s_o[c2];
        dc_layer(hreg[1], oa, ob, hreg[2], h2a, h2b, v, vv, c1, c2, act, n,
                 Wg + 24, Bg[4], Bg[5], Wc + 12, Cb[2], s_rh);
        float proj = hreg[2] * projw + projb;
        if (act) {
            s_h[q][2][n] = hreg[2];
            s_x[q][n] = proj;                    // stage next decoder input
            outp[((size_t)b * NNODE + n) * TT + t] = proj;
        }
        __syncthreads();
        dinp = proj; p = q;
    }
}

// ---------------- host launcher ---------------------------------------------
extern "C" void kernel_launch(void* const* d_in, const int* in_sizes, int n_in,
                              void* d_out, int out_size, void* d_ws, size_t ws_size,
                              hipStream_t stream)
{
    (void)in_sizes; (void)n_in; (void)out_size; (void)ws_size;
    const float* full_seq = (const float*)d_in[0];   // (M,64,8)
    const float* rec_seq  = (const float*)d_in[1];   // (32,360,64)
    const float* temp     = (const float*)d_in[3];
    const float* g0wih    = (const float*)d_in[4];
    const float* g0whh    = (const float*)d_in[5];
    const float* g0bih    = (const float*)d_in[6];
    const float* g0bhh    = (const float*)d_in[7];
    const float* gwih     = (const float*)d_in[8];   // (3,2,24,16)
    const float* gwhh     = (const float*)d_in[9];   // (3,2,24,8)
    const float* gbih     = (const float*)d_in[10];
    const float* gbhh     = (const float*)d_in[11];
    const float* l1w      = (const float*)d_in[12];
    const float* l1b      = (const float*)d_in[13];
    const float* l2w      = (const float*)d_in[14];
    const float* l2b      = (const float*)d_in[15];
    const float* enc_gw   = (const float*)d_in[16];
    const float* enc_gb   = (const float*)d_in[17];
    const float* enc_cw   = (const float*)d_in[18];
    const float* enc_cb   = (const float*)d_in[19];
    const float* dec_gw   = (const float*)d_in[20];
    const float* dec_gb   = (const float*)d_in[21];
    const float* dec_cw   = (const float*)d_in[22];
    const float* dec_cb   = (const float*)d_in[23];
    const float* proj_w   = (const float*)d_in[24];
    const float* proj_b   = (const float*)d_in[25];
    float* outp = (float*)d_out;

    // ws: small-first; bufA+bufB ping-pong = 94.85 MB total (proven size)
    float* ws   = (float*)d_ws;
    float* feat = ws;                                     // (M,8)
    float* vbuf = feat + (size_t)M_SEQ * 8;               // (M,)
    int*   cbuf = (int*)(vbuf + M_SEQ);                   // (M,)
    float* bufA = (float*)(cbuf + M_SEQ);                 // (M,64,16)
    float* bufB = bufA + (size_t)M_SEQ * TT * 16;         // (M,64,16)

    const int ggru = (M_SEQ * 2 * 8) / 256;   // 720 blocks
    gru_fused<8><<<ggru, 256, 0, stream>>>(full_seq, g0wih, g0whh, g0bih, g0bhh, bufA);
    gru_fused<16><<<ggru, 256, 0, stream>>>(bufA, gwih + 0 * 768, gwhh + 0 * 384,
                                            gbih + 0 * 48, gbhh + 0 * 48, bufB);
    gru_fused<16><<<ggru, 256, 0, stream>>>(bufB, gwih + 1 * 768, gwhh + 1 * 384,
                                            gbih + 1 * 48, gbhh + 1 * 48, bufA);
    gru_fused<16><<<ggru, 256, 0, stream>>>(bufA, gwih + 2 * 768, gwhh + 2 * 384,
                                            gbih + 2 * 48, gbhh + 2 * 48, bufB);
    feat_kernel<<<M_SEQ / 256, 256, 0, stream>>>(bufB, l1w, l1b, l2w, l2b, feat);
    adj_kernel<<<(NB * NNODE) / 4, 256, 0, stream>>>(feat, temp, cbuf, vbuf);
    decode_kernel<<<NB, 384, 0, stream>>>(rec_seq, cbuf, vbuf,
                                          enc_gw, enc_gb, enc_cw, enc_cb,
                                          dec_gw, dec_gb, dec_cw, dec_cb,
                                          proj_w, proj_b, outp);
}